// Round 4
// baseline (4135.029 us; speedup 1.0000x reference)
//
#include <hip/hip_runtime.h>
#include <math.h>

// ==================== int32/int64 index handling ====================
// Reference declares edge_index/batch as int64; harness doc says int32.
// Detect on device (graph-capture safe): for int64 little-endian values
// < 2^31, every odd int32 slot is 0. Random int32 edge data cannot have
// 1024 consecutive zero odd-slots.
__device__ __forceinline__ int idx_at(const void* p, long long i, int is64) {
    if (is64) return (int)((const long long*)p)[i];
    return ((const int*)p)[i];
}

__global__ void detect_kernel(const int* __restrict__ ei, int E, int* __restrict__ flag) {
    __shared__ int any;
    if (threadIdx.x == 0) any = 0;
    __syncthreads();
    int n = min(E, 1024);
    for (int i = threadIdx.x; i < n; i += blockDim.x)
        if (ei[2 * i + 1] != 0) any = 1;
    __syncthreads();
    if (threadIdx.x == 0) *flag = (any == 0) ? 1 : 0;
}

// ============================ CSR build ============================

__global__ void hist_kernel(const void* __restrict__ idx, long long offs,
                            const int* __restrict__ flag,
                            int* __restrict__ cnt, int n) {
    int is64 = *flag;
    int i = blockIdx.x * blockDim.x + threadIdx.x;
    if (i < n) atomicAdd(&cnt[idx_at(idx, offs + i, is64)], 1);
}

__global__ void scan_kernel(const int* __restrict__ cnt, int* __restrict__ ofs, int n) {
    __shared__ int buf[1024];
    __shared__ int carry;
    int tid = threadIdx.x;
    if (tid == 0) { carry = 0; ofs[0] = 0; }
    __syncthreads();
    for (int base = 0; base < n; base += 1024) {
        int v = (base + tid < n) ? cnt[base + tid] : 0;
        buf[tid] = v;
        __syncthreads();
        for (int off = 1; off < 1024; off <<= 1) {
            int t = (tid >= off) ? buf[tid - off] : 0;
            __syncthreads();
            buf[tid] += t;
            __syncthreads();
        }
        if (base + tid < n) ofs[base + tid + 1] = carry + buf[tid];
        __syncthreads();
        if (tid == 0) carry += buf[1023];
        __syncthreads();
    }
}

__global__ void fill_csr_kernel(const void* __restrict__ ei, long long E,
                                const int* __restrict__ flag,
                                int* __restrict__ cursor, int* __restrict__ esrc, int e) {
    int is64 = *flag;
    int i = blockIdx.x * blockDim.x + threadIdx.x;
    if (i < e) {
        int d = idx_at(ei, E + i, is64);
        int s = idx_at(ei, i, is64);
        int p = atomicAdd(&cursor[d], 1);
        esrc[p] = s;
    }
}

__global__ void copy_int_kernel(const int* __restrict__ a, int* __restrict__ b, int n) {
    int i = blockIdx.x * blockDim.x + threadIdx.x;
    if (i < n) b[i] = a[i];
}

// ======================= Aggregation (GIN) =========================
// z[i] = scale * (u[i] + sum_{j in in(i)} u[j]) + (1+deg_i) * shift
// scale==nullptr -> identity (layer 0 input x).
__global__ void aggregate_kernel(const float* __restrict__ X,
                                 const int* __restrict__ row_ofs,
                                 const int* __restrict__ esrc,
                                 const float* __restrict__ scale,
                                 const float* __restrict__ shift,
                                 float* __restrict__ Z,
                                 int n, int ncols) {
    int tpr = ncols >> 2;                       // threads per row (float4 each)
    int nper = blockDim.x / tpr;                // rows per block
    int node = blockIdx.x * nper + threadIdx.x / tpr;
    int c = (threadIdx.x % tpr) * 4;
    if (node >= n) return;
    int beg = row_ofs[node], end = row_ofs[node + 1];
    float4 acc = *reinterpret_cast<const float4*>(X + (size_t)node * ncols + c);
    for (int e = beg; e < end; ++e) {
        int s = esrc[e];
        float4 v = *reinterpret_cast<const float4*>(X + (size_t)s * ncols + c);
        acc.x += v.x; acc.y += v.y; acc.z += v.z; acc.w += v.w;
    }
    if (scale) {
        float d1 = (float)(end - beg + 1);
        float4 sc = *reinterpret_cast<const float4*>(scale + c);
        float4 sh = *reinterpret_cast<const float4*>(shift + c);
        acc.x = sc.x * acc.x + d1 * sh.x;
        acc.y = sc.y * acc.y + d1 * sh.y;
        acc.z = sc.z * acc.z + d1 * sh.z;
        acc.w = sc.w * acc.w + d1 * sh.w;
    }
    *reinterpret_cast<float4*>(Z + (size_t)node * ncols + c) = acc;
}

// ============================ GEMM =================================
// C[M x 512] = act(A[M x K] @ W[K x 512] + bias). ACT: 0 = relu, 1 = tanh.
#define BM 128
#define BN 128
#define BK 16
#define LPAD 4

template <int ACT>
__global__ __launch_bounds__(256)
void gemm_kernel(const float* __restrict__ A, const float* __restrict__ W,
                 const float* __restrict__ bias, float* __restrict__ C,
                 int M, int K) {
    __shared__ float As[BK][BM + LPAD];   // A stored transposed: As[k][m]
    __shared__ float Bs[BK][BN + LPAD];

    const int tid = threadIdx.x;
    const int tx = tid & 15;
    const int ty = tid >> 4;
    const int row0 = blockIdx.x * BM;
    const int col0 = blockIdx.y * BN;

    float acc[8][8];
#pragma unroll
    for (int i = 0; i < 8; ++i)
#pragma unroll
        for (int j = 0; j < 8; ++j) acc[i][j] = 0.f;

    const int nk = K / BK;
    for (int kt = 0; kt < nk; ++kt) {
        const int k0 = kt * BK;
#pragma unroll
        for (int i = 0; i < 2; ++i) {           // A: 2 x float4 per thread
            int f = tid + i * 256;              // 0..511
            int r = f >> 2;                     // 0..127
            int kc = (f & 3) * 4;               // 0,4,8,12
            int rg = row0 + r;
            float4 v = make_float4(0.f, 0.f, 0.f, 0.f);
            if (rg < M)
                v = *reinterpret_cast<const float4*>(&A[(size_t)rg * K + k0 + kc]);
            As[kc + 0][r] = v.x;
            As[kc + 1][r] = v.y;
            As[kc + 2][r] = v.z;
            As[kc + 3][r] = v.w;
        }
#pragma unroll
        for (int i = 0; i < 2; ++i) {           // B: 2 x float4 per thread
            int f = tid + i * 256;
            int kr = f >> 5;                    // 0..15
            int c4 = (f & 31) * 4;              // 0..124
            float4 v = *reinterpret_cast<const float4*>(&W[(size_t)(k0 + kr) * 512 + col0 + c4]);
            *reinterpret_cast<float4*>(&Bs[kr][c4]) = v;
        }
        __syncthreads();
#pragma unroll
        for (int k = 0; k < BK; ++k) {
            float a[8], b[8];
            *reinterpret_cast<float4*>(&a[0]) = *reinterpret_cast<const float4*>(&As[k][ty * 8]);
            *reinterpret_cast<float4*>(&a[4]) = *reinterpret_cast<const float4*>(&As[k][ty * 8 + 4]);
            *reinterpret_cast<float4*>(&b[0]) = *reinterpret_cast<const float4*>(&Bs[k][tx * 8]);
            *reinterpret_cast<float4*>(&b[4]) = *reinterpret_cast<const float4*>(&Bs[k][tx * 8 + 4]);
#pragma unroll
            for (int i = 0; i < 8; ++i)
#pragma unroll
                for (int j = 0; j < 8; ++j)
                    acc[i][j] = fmaf(a[i], b[j], acc[i][j]);
        }
        __syncthreads();
    }

    float bv[8];
#pragma unroll
    for (int j = 0; j < 8; ++j) bv[j] = bias[col0 + tx * 8 + j];
#pragma unroll
    for (int i = 0; i < 8; ++i) {
        int rg = row0 + ty * 8 + i;
        if (rg < M) {
            float o[8];
#pragma unroll
            for (int j = 0; j < 8; ++j) {
                float v = acc[i][j] + bv[j];
                if (ACT == 0) v = fmaxf(v, 0.f);
                else          v = tanhf(v);
                o[j] = v;
            }
            float* cp = &C[(size_t)rg * 512 + col0 + tx * 8];
            *reinterpret_cast<float4*>(cp)     = *reinterpret_cast<float4*>(&o[0]);
            *reinterpret_cast<float4*>(cp + 4) = *reinterpret_cast<float4*>(&o[4]);
        }
    }
}

// ======================= Column stats for BN =======================
__global__ void stats_kernel(const float* __restrict__ H, float* __restrict__ stats, int M) {
    int c = threadIdx.x * 4;                    // 128 threads -> 512 cols
    int r0 = blockIdx.x * 128;
    int r1 = min(r0 + 128, M);
    float4 s = make_float4(0.f, 0.f, 0.f, 0.f);
    float4 q = make_float4(0.f, 0.f, 0.f, 0.f);
    for (int r = r0; r < r1; ++r) {
        float4 v = *reinterpret_cast<const float4*>(H + (size_t)r * 512 + c);
        s.x += v.x; s.y += v.y; s.z += v.z; s.w += v.w;
        q.x += v.x * v.x; q.y += v.y * v.y; q.z += v.z * v.z; q.w += v.w * v.w;
    }
    atomicAdd(&stats[c + 0], s.x); atomicAdd(&stats[c + 1], s.y);
    atomicAdd(&stats[c + 2], s.z); atomicAdd(&stats[c + 3], s.w);
    atomicAdd(&stats[512 + c + 0], q.x); atomicAdd(&stats[512 + c + 1], q.y);
    atomicAdd(&stats[512 + c + 2], q.z); atomicAdd(&stats[512 + c + 3], q.w);
}

__global__ void bn_params_kernel(const float* __restrict__ stats,
                                 const float* __restrict__ gamma,
                                 const float* __restrict__ beta,
                                 float* __restrict__ scale, float* __restrict__ shift,
                                 float invN) {
    int c = blockIdx.x * blockDim.x + threadIdx.x;
    if (c >= 512) return;
    float mean = stats[c] * invN;
    float var = fmaxf(stats[512 + c] * invN - mean * mean, 0.f);
    float a = gamma[c] * rsqrtf(var + 1e-5f);
    scale[c] = a;
    shift[c] = beta[c] - mean * a;
}

// =========================== Pooling ===============================
#define POOL_ROWS 64
__global__ void pool_kernel(const float* __restrict__ H, const void* __restrict__ batch,
                            const int* __restrict__ flag,
                            float* __restrict__ pooled, int n) {
    int is64 = *flag;
    int c = threadIdx.x * 4;
    int r0 = blockIdx.x * POOL_ROWS;
    if (r0 >= n) return;
    int r1 = min(r0 + POOL_ROWS, n);
    int g = idx_at(batch, r0, is64);
    float4 acc = make_float4(0.f, 0.f, 0.f, 0.f);
    for (int r = r0; r < r1; ++r) {
        int gr = idx_at(batch, r, is64);
        if (gr != g) {
            atomicAdd(&pooled[(size_t)g * 512 + c + 0], acc.x);
            atomicAdd(&pooled[(size_t)g * 512 + c + 1], acc.y);
            atomicAdd(&pooled[(size_t)g * 512 + c + 2], acc.z);
            atomicAdd(&pooled[(size_t)g * 512 + c + 3], acc.w);
            acc = make_float4(0.f, 0.f, 0.f, 0.f);
            g = gr;
        }
        float4 v = *reinterpret_cast<const float4*>(H + (size_t)r * 512 + c);
        acc.x += v.x; acc.y += v.y; acc.z += v.z; acc.w += v.w;
    }
    atomicAdd(&pooled[(size_t)g * 512 + c + 0], acc.x);
    atomicAdd(&pooled[(size_t)g * 512 + c + 1], acc.y);
    atomicAdd(&pooled[(size_t)g * 512 + c + 2], acc.z);
    atomicAdd(&pooled[(size_t)g * 512 + c + 3], acc.w);
}

// pooled mean + fold layer-5 BN affine
__global__ void finalize_pool_kernel(const float* __restrict__ pooled,
                                     const int* __restrict__ cg,
                                     const float* __restrict__ scale,
                                     const float* __restrict__ shift,
                                     float* __restrict__ Apool, int total) {
    int idx = blockIdx.x * blockDim.x + threadIdx.x;
    if (idx >= total) return;
    int g = idx >> 9;
    int c = idx & 511;
    float cnt = fmaxf((float)cg[g], 1.f);
    Apool[idx] = scale[c] * (pooled[idx] / cnt) + shift[c];
}

// =========================== Launcher ==============================
extern "C" void kernel_launch(void* const* d_in, const int* in_sizes, int n_in,
                              void* d_out, int out_size, void* d_ws, size_t ws_size,
                              hipStream_t stream) {
    const float* x      = (const float*)d_in[0];
    const void*  ei     = d_in[1];
    const void*  batch  = d_in[2];
    const float* W1a    = (const float*)d_in[3];
    const float* b1a    = (const float*)d_in[4];
    const float* W1b    = (const float*)d_in[5];
    const float* b1b    = (const float*)d_in[6];
    const float* Wa     = (const float*)d_in[7];
    const float* ba     = (const float*)d_in[8];
    const float* Wb     = (const float*)d_in[9];
    const float* bb     = (const float*)d_in[10];
    const float* gammas = (const float*)d_in[11];
    const float* betas  = (const float*)d_in[12];
    const float* fcW    = (const float*)d_in[13];
    const float* fcb    = (const float*)d_in[14];

    const int N = in_sizes[2];                 // 50000 nodes
    const int E = in_sizes[1] / 2;             // 150000 edges
    const int F = in_sizes[0] / N;             // 128
    const int G = out_size / 512;              // 256 graphs

    // ---- workspace layout (bump allocator, 256B aligned) ----
    // Big buffers: ping-pong pair only (~205 MB total ws), not 3.
    char* w = (char*)d_ws;
    size_t off = 0;
    auto alloc = [&](size_t bytes) -> void* {
        void* p = w + off;
        off = (off + bytes + 255) & ~(size_t)255;
        return p;
    };
    float* bufA   = (float*)alloc((size_t)N * 512 * 4);
    float* bufB   = (float*)alloc((size_t)N * 512 * 4);
    int*   row_ofs= (int*)alloc((size_t)(N + 1) * 4);
    int*   cnt    = (int*)alloc((size_t)N * 4);     // reused as cursor after scan
    int*   esrc   = (int*)alloc((size_t)E * 4);
    int*   cg     = (int*)alloc((size_t)G * 4);
    float* stats  = (float*)alloc(1024 * 4);
    float* scale  = (float*)alloc(512 * 4);
    float* shift  = (float*)alloc(512 * 4);
    float* pooled = (float*)alloc((size_t)G * 512 * 4);
    float* Apool  = (float*)alloc((size_t)G * 512 * 4);
    int*   flag   = (int*)alloc(256);
    (void)ws_size; (void)n_in;

    // ---- int width detection + CSR build (every call; ws re-poisoned) ----
    detect_kernel<<<1, 256, 0, stream>>>((const int*)ei, E, flag);
    hipMemsetAsync(cnt, 0, (size_t)N * 4, stream);
    hist_kernel<<<(E + 255) / 256, 256, 0, stream>>>(ei, (long long)E, flag, cnt, E);
    scan_kernel<<<1, 1024, 0, stream>>>(cnt, row_ofs, N);
    // cnt is dead after scan; reuse as cursor
    copy_int_kernel<<<(N + 255) / 256, 256, 0, stream>>>(row_ofs, cnt, N);
    fill_csr_kernel<<<(E + 255) / 256, 256, 0, stream>>>(ei, (long long)E, flag, cnt, esrc, E);
    hipMemsetAsync(cg, 0, (size_t)G * 4, stream);
    hist_kernel<<<(N + 255) / 256, 256, 0, stream>>>(batch, 0, flag, cg, N);

    // ---- 5 GIN blocks (ping-pong: agg curH->Zb, gemm1 Zb->Tb, gemm2 Tb->Zb) ----
    const float* curH = x;
    int ncols = F;
    const float* scaleP = nullptr;
    const float* shiftP = nullptr;
    float* Zb = bufA;
    float* Tb = bufB;
    for (int L = 0; L < 5; ++L) {
        int tpr = ncols / 4;
        int nper = 128 / tpr;
        aggregate_kernel<<<(N + nper - 1) / nper, 128, 0, stream>>>(
            curH, row_ofs, esrc, scaleP, shiftP, Zb, N, ncols);

        const float* Wa_ = (L == 0) ? W1a : Wa + (size_t)(L - 1) * 512 * 512;
        const float* ba_ = (L == 0) ? b1a : ba + (size_t)(L - 1) * 512;
        const float* Wb_ = (L == 0) ? W1b : Wb + (size_t)(L - 1) * 512 * 512;
        const float* bb_ = (L == 0) ? b1b : bb + (size_t)(L - 1) * 512;

        dim3 g1((N + BM - 1) / BM, 512 / BN);
        gemm_kernel<0><<<g1, 256, 0, stream>>>(Zb, Wa_, ba_, Tb, N, ncols);   // Zb dead after
        gemm_kernel<0><<<g1, 256, 0, stream>>>(Tb, Wb_, bb_, Zb, N, 512);     // H -> Zb

        hipMemsetAsync(stats, 0, 1024 * 4, stream);
        stats_kernel<<<(N + 127) / 128, 128, 0, stream>>>(Zb, stats, N);
        bn_params_kernel<<<2, 256, 0, stream>>>(stats, gammas + (size_t)L * 512,
                                                betas + (size_t)L * 512,
                                                scale, shift, 1.f / (float)N);
        curH = Zb;
        ncols = 512;
        scaleP = scale;
        shiftP = shift;
        float* tmp = Zb; Zb = Tb; Tb = tmp;   // swap roles for next layer
    }
    const float* Hfin = curH;

    // ---- global mean pool (+ fold BN5) ----
    hipMemsetAsync(pooled, 0, (size_t)G * 512 * 4, stream);
    pool_kernel<<<(N + POOL_ROWS - 1) / POOL_ROWS, 128, 0, stream>>>(Hfin, batch, flag, pooled, N);
    int total = G * 512;
    finalize_pool_kernel<<<(total + 255) / 256, 256, 0, stream>>>(pooled, cg, scale, shift,
                                                                  Apool, total);

    // ---- final fc + tanh ----
    dim3 g2((G + BM - 1) / BM, 512 / BN);
    gemm_kernel<1><<<g2, 256, 0, stream>>>(Apool, fcW, fcb, (float*)d_out, G, 512);
}

// Round 5
// 1865.271 us; speedup vs baseline: 2.2169x; 2.2169x over previous
//
#include <hip/hip_runtime.h>
#include <math.h>

typedef unsigned short u16;
typedef unsigned int u32;
typedef __attribute__((ext_vector_type(8))) short bf16x8;   // 8 bf16 = 4 VGPRs
typedef __attribute__((ext_vector_type(4))) float f32x4;

__device__ __forceinline__ u16 f2bf(float x) {              // RNE float->bf16
    u32 u = __float_as_uint(x);
    return (u16)((u + 0x7FFFu + ((u >> 16) & 1u)) >> 16);
}
__device__ __forceinline__ float bf2f(u16 h) {
    return __uint_as_float(((u32)h) << 16);
}
__device__ __forceinline__ void async16(const void* g, void* l) {
    __builtin_amdgcn_global_load_lds((const __attribute__((address_space(1))) void*)g,
                                     (__attribute__((address_space(3))) void*)l,
                                     16, 0, 0);
}

// ==================== int32/int64 index handling ====================
__device__ __forceinline__ int idx_at(const void* p, long long i, int is64) {
    if (is64) return (int)((const long long*)p)[i];
    return ((const int*)p)[i];
}

__global__ void detect_kernel(const int* __restrict__ ei, int E, int* __restrict__ flag) {
    __shared__ int any;
    if (threadIdx.x == 0) any = 0;
    __syncthreads();
    int n = min(E, 1024);
    for (int i = threadIdx.x; i < n; i += blockDim.x)
        if (ei[2 * i + 1] != 0) any = 1;
    __syncthreads();
    if (threadIdx.x == 0) *flag = (any == 0) ? 1 : 0;
}

// ============================ CSR build ============================
__global__ void hist_kernel(const void* __restrict__ idx, long long offs,
                            const int* __restrict__ flag,
                            int* __restrict__ cnt, int n) {
    int is64 = *flag;
    int i = blockIdx.x * blockDim.x + threadIdx.x;
    if (i < n) atomicAdd(&cnt[idx_at(idx, offs + i, is64)], 1);
}

__global__ void scan_kernel(const int* __restrict__ cnt, int* __restrict__ ofs, int n) {
    __shared__ int buf[1024];
    __shared__ int carry;
    int tid = threadIdx.x;
    if (tid == 0) { carry = 0; ofs[0] = 0; }
    __syncthreads();
    for (int base = 0; base < n; base += 1024) {
        int v = (base + tid < n) ? cnt[base + tid] : 0;
        buf[tid] = v;
        __syncthreads();
        for (int off = 1; off < 1024; off <<= 1) {
            int t = (tid >= off) ? buf[tid - off] : 0;
            __syncthreads();
            buf[tid] += t;
            __syncthreads();
        }
        if (base + tid < n) ofs[base + tid + 1] = carry + buf[tid];
        __syncthreads();
        if (tid == 0) carry += buf[1023];
        __syncthreads();
    }
}

__global__ void fill_csr_kernel(const void* __restrict__ ei, long long E,
                                const int* __restrict__ flag,
                                int* __restrict__ cursor, int* __restrict__ esrc, int e) {
    int is64 = *flag;
    int i = blockIdx.x * blockDim.x + threadIdx.x;
    if (i < e) {
        int d = idx_at(ei, E + i, is64);
        int s = idx_at(ei, i, is64);
        int p = atomicAdd(&cursor[d], 1);
        esrc[p] = s;
    }
}

__global__ void copy_int_kernel(const int* __restrict__ a, int* __restrict__ b, int n) {
    int i = blockIdx.x * blockDim.x + threadIdx.x;
    if (i < n) b[i] = a[i];
}

// ================ Aggregation (GIN) + BN fold + bf16 split ================
// z = scale*(u_i + sum_j u_j) + (1+deg)*shift   (scale==nullptr -> identity)
// Output: split bf16 (hi + lo captures ~fp32 precision).
__global__ void aggregate_split_kernel(const float* __restrict__ X,
                                       const int* __restrict__ row_ofs,
                                       const int* __restrict__ esrc,
                                       const float* __restrict__ scale,
                                       const float* __restrict__ shift,
                                       u16* __restrict__ Zhi, u16* __restrict__ Zlo,
                                       int n, int ncols) {
    int tpr = ncols >> 2;
    int nper = blockDim.x / tpr;
    int node = blockIdx.x * nper + threadIdx.x / tpr;
    int c = (threadIdx.x % tpr) * 4;
    if (node >= n) return;
    int beg = row_ofs[node], end = row_ofs[node + 1];
    float4 acc = *reinterpret_cast<const float4*>(X + (size_t)node * ncols + c);
    for (int e = beg; e < end; ++e) {
        int s = esrc[e];
        float4 v = *reinterpret_cast<const float4*>(X + (size_t)s * ncols + c);
        acc.x += v.x; acc.y += v.y; acc.z += v.z; acc.w += v.w;
    }
    if (scale) {
        float d1 = (float)(end - beg + 1);
        float4 sc = *reinterpret_cast<const float4*>(scale + c);
        float4 sh = *reinterpret_cast<const float4*>(shift + c);
        acc.x = sc.x * acc.x + d1 * sh.x;
        acc.y = sc.y * acc.y + d1 * sh.y;
        acc.z = sc.z * acc.z + d1 * sh.z;
        acc.w = sc.w * acc.w + d1 * sh.w;
    }
    ushort4 hv, lv;
    hv.x = f2bf(acc.x); lv.x = f2bf(acc.x - bf2f(hv.x));
    hv.y = f2bf(acc.y); lv.y = f2bf(acc.y - bf2f(hv.y));
    hv.z = f2bf(acc.z); lv.z = f2bf(acc.z - bf2f(hv.z));
    hv.w = f2bf(acc.w); lv.w = f2bf(acc.w - bf2f(hv.w));
    *reinterpret_cast<ushort4*>(Zhi + (size_t)node * ncols + c) = hv;
    *reinterpret_cast<ushort4*>(Zlo + (size_t)node * ncols + c) = lv;
}

// ============== Weight transpose + bf16 split (per launch) ==============
// W (K x N, f32) -> WT_hi/WT_lo (N x K, bf16)
__global__ void transpose_split_kernel(const float* __restrict__ W, int K, int N,
                                       u16* __restrict__ Thi, u16* __restrict__ Tlo) {
    __shared__ float t[32][33];
    int k0 = blockIdx.x * 32, n0 = blockIdx.y * 32;
    int tx = threadIdx.x & 31, ty = threadIdx.x >> 5;      // 32 x 8
#pragma unroll
    for (int i = 0; i < 32; i += 8)
        t[ty + i][tx] = W[(size_t)(k0 + ty + i) * N + n0 + tx];
    __syncthreads();
#pragma unroll
    for (int i = 0; i < 32; i += 8) {
        float v = t[tx][ty + i];                            // W[k0+tx][n0+ty+i]
        size_t o = (size_t)(n0 + ty + i) * K + k0 + tx;
        u16 h = f2bf(v);
        Thi[o] = h;
        Tlo[o] = f2bf(v - bf2f(h));
    }
}

// ======================= split-bf16 MFMA GEMM =======================
// C[M x 512] = act(A @ W + bias), A as (Ahi+Alo) M x K bf16 row-major,
// W as WT (Bhi+Blo) 512 x K bf16 row-major (i.e. W transposed).
// 3-term: hiA*hiB + hiA*loB + loA*hiB  (~fp32 precision, fp32 accum).
// MODE 0: relu -> split-bf16 out (Ohi/Olo).  MODE 1: relu -> f32 out + fused BN col stats.
// blockIdx.x = N-block (4), blockIdx.y = M-block  (A read once from HBM; B L2-resident)
template <int MODE>
__global__ __launch_bounds__(256, 2)
void gemm_mfma(const u16* __restrict__ Ahi, const u16* __restrict__ Alo,
               const u16* __restrict__ Bhi, const u16* __restrict__ Blo,
               const float* __restrict__ bias, int M, int K,
               u16* __restrict__ Ohi, u16* __restrict__ Olo,
               float* __restrict__ Of32, float* __restrict__ stats) {
    __shared__ __align__(16) char lds[65536];
    char* ldsAhi = lds;
    char* ldsAlo = lds + 16384;
    char* ldsBhi = lds + 32768;
    char* ldsBlo = lds + 49152;

    const int tid = threadIdx.x;
    const int lane = tid & 63;
    const int wave = tid >> 6;
    const int wr = wave >> 1, wc = wave & 1;   // 2x2 waves, each 64x64 out
    const int col0 = blockIdx.x * 128;
    const int row0 = blockIdx.y * 128;

    f32x4 acc[4][4];
#pragma unroll
    for (int mi = 0; mi < 4; ++mi)
#pragma unroll
        for (int ni = 0; ni < 4; ++ni)
            acc[mi][ni] = (f32x4){0.f, 0.f, 0.f, 0.f};

    const int nkt = K >> 6;                    // BK = 64
    for (int kt = 0; kt < nkt; ++kt) {
        const int k0 = kt << 6;
        // ---- stage 4 tiles (128x64 bf16 each) via global_load_lds ----
        // LDS slot (row, s) holds global k-chunk (s ^ (row&7))  [XOR swizzle,
        // applied on the SOURCE address; LDS dest stays lane-linear]
#pragma unroll
        for (int i = 0; i < 4; ++i) {
            int c = tid + i * 256;             // 0..1023
            int row = c >> 3, s = c & 7;
            int ks = ((s ^ (row & 7)) << 3);   // element offset in BK
            int ar = row0 + row; if (ar > M - 1) ar = M - 1;
            size_t aoff = (size_t)ar * K + k0 + ks;
            size_t boff = (size_t)(col0 + row) * K + k0 + ks;
            async16(Ahi + aoff, ldsAhi + c * 16);
            async16(Alo + aoff, ldsAlo + c * 16);
            async16(Bhi + boff, ldsBhi + c * 16);
            async16(Blo + boff, ldsBlo + c * 16);
        }
        __syncthreads();                        // drains vmcnt before barrier
        // ---- 2 x K=32 MFMA sub-steps ----
#pragma unroll
        for (int kk = 0; kk < 2; ++kk) {
            bf16x8 ah[4], al[4], bh[4], bl[4];
            const int kc = (kk << 2) + (lane >> 4);   // 8-elem chunk idx in BK
#pragma unroll
            for (int mi = 0; mi < 4; ++mi) {
                int ml = wr * 64 + mi * 16 + (lane & 15);
                int off = ml * 128 + ((kc ^ (ml & 7)) << 4);
                ah[mi] = *(const bf16x8*)(ldsAhi + off);
                al[mi] = *(const bf16x8*)(ldsAlo + off);
            }
#pragma unroll
            for (int ni = 0; ni < 4; ++ni) {
                int nl = wc * 64 + ni * 16 + (lane & 15);
                int off = nl * 128 + ((kc ^ (nl & 7)) << 4);
                bh[ni] = *(const bf16x8*)(ldsBhi + off);
                bl[ni] = *(const bf16x8*)(ldsBlo + off);
            }
#pragma unroll
            for (int mi = 0; mi < 4; ++mi)
#pragma unroll
                for (int ni = 0; ni < 4; ++ni) {
                    acc[mi][ni] = __builtin_amdgcn_mfma_f32_16x16x32_bf16(
                        ah[mi], bh[ni], acc[mi][ni], 0, 0, 0);
                    acc[mi][ni] = __builtin_amdgcn_mfma_f32_16x16x32_bf16(
                        ah[mi], bl[ni], acc[mi][ni], 0, 0, 0);
                    acc[mi][ni] = __builtin_amdgcn_mfma_f32_16x16x32_bf16(
                        al[mi], bh[ni], acc[mi][ni], 0, 0, 0);
                }
        }
        __syncthreads();
    }

    // ---- epilogue: C/D layout col=lane&15, row=(lane>>4)*4+reg [m89] ----
    const int cl = lane & 15;
    const int rb = (lane >> 4) * 4;
    if (MODE == 0) {
#pragma unroll
        for (int ni = 0; ni < 4; ++ni) {
            int gc = col0 + wc * 64 + ni * 16 + cl;
            float bv = bias[gc];
#pragma unroll
            for (int mi = 0; mi < 4; ++mi) {
                int gr0 = row0 + wr * 64 + mi * 16 + rb;
#pragma unroll
                for (int r = 0; r < 4; ++r) {
                    int gr = gr0 + r;
                    if (gr < M) {
                        float v = fmaxf(acc[mi][ni][r] + bv, 0.f);
                        u16 h = f2bf(v);
                        Ohi[(size_t)gr * 512 + gc] = h;
                        Olo[(size_t)gr * 512 + gc] = f2bf(v - bf2f(h));
                    }
                }
            }
        }
    } else {
#pragma unroll
        for (int ni = 0; ni < 4; ++ni) {
            int gc = col0 + wc * 64 + ni * 16 + cl;
            float bv = bias[gc];
            float s = 0.f, q = 0.f;
#pragma unroll
            for (int mi = 0; mi < 4; ++mi) {
                int gr0 = row0 + wr * 64 + mi * 16 + rb;
#pragma unroll
                for (int r = 0; r < 4; ++r) {
                    int gr = gr0 + r;
                    if (gr < M) {
                        float v = fmaxf(acc[mi][ni][r] + bv, 0.f);
                        Of32[(size_t)gr * 512 + gc] = v;
                        s += v; q += v * v;
                    }
                }
            }
            s += __shfl_xor(s, 16); s += __shfl_xor(s, 32);
            q += __shfl_xor(q, 16); q += __shfl_xor(q, 32);
            if (lane < 16) {
                atomicAdd(&stats[gc], s);
                atomicAdd(&stats[512 + gc], q);
            }
        }
    }
}

// ======================= BN params from stats =======================
__global__ void bn_params_kernel(const float* __restrict__ stats,
                                 const float* __restrict__ gamma,
                                 const float* __restrict__ beta,
                                 float* __restrict__ scale, float* __restrict__ shift,
                                 float invN) {
    int c = blockIdx.x * blockDim.x + threadIdx.x;
    if (c >= 512) return;
    float mean = stats[c] * invN;
    float var = fmaxf(stats[512 + c] * invN - mean * mean, 0.f);
    float a = gamma[c] * rsqrtf(var + 1e-5f);
    scale[c] = a;
    shift[c] = beta[c] - mean * a;
}

// =========================== Pooling ===============================
#define POOL_ROWS 64
__global__ void pool_kernel(const float* __restrict__ H, const void* __restrict__ batch,
                            const int* __restrict__ flag,
                            float* __restrict__ pooled, int n) {
    int is64 = *flag;
    int c = threadIdx.x * 4;
    int r0 = blockIdx.x * POOL_ROWS;
    if (r0 >= n) return;
    int r1 = min(r0 + POOL_ROWS, n);
    int g = idx_at(batch, r0, is64);
    float4 acc = make_float4(0.f, 0.f, 0.f, 0.f);
    for (int r = r0; r < r1; ++r) {
        int gr = idx_at(batch, r, is64);
        if (gr != g) {
            atomicAdd(&pooled[(size_t)g * 512 + c + 0], acc.x);
            atomicAdd(&pooled[(size_t)g * 512 + c + 1], acc.y);
            atomicAdd(&pooled[(size_t)g * 512 + c + 2], acc.z);
            atomicAdd(&pooled[(size_t)g * 512 + c + 3], acc.w);
            acc = make_float4(0.f, 0.f, 0.f, 0.f);
            g = gr;
        }
        float4 v = *reinterpret_cast<const float4*>(H + (size_t)r * 512 + c);
        acc.x += v.x; acc.y += v.y; acc.z += v.z; acc.w += v.w;
    }
    atomicAdd(&pooled[(size_t)g * 512 + c + 0], acc.x);
    atomicAdd(&pooled[(size_t)g * 512 + c + 1], acc.y);
    atomicAdd(&pooled[(size_t)g * 512 + c + 2], acc.z);
    atomicAdd(&pooled[(size_t)g * 512 + c + 3], acc.w);
}

__global__ void finalize_pool_kernel(const float* __restrict__ pooled,
                                     const int* __restrict__ cg,
                                     const float* __restrict__ scale,
                                     const float* __restrict__ shift,
                                     float* __restrict__ Apool, int total) {
    int idx = blockIdx.x * blockDim.x + threadIdx.x;
    if (idx >= total) return;
    int g = idx >> 9;
    int c = idx & 511;
    float cnt = fmaxf((float)cg[g], 1.f);
    Apool[idx] = scale[c] * (pooled[idx] / cnt) + shift[c];
}

// ================== final fc + tanh (small M, fp32 acc) ==================
// out[m][n] = tanh( sum_k A[m][k] * (WThi[n][k]+WTlo[n][k]) + b[n] )
__global__ void fc_tanh_kernel(const float* __restrict__ A,
                               const u16* __restrict__ WThi, const u16* __restrict__ WTlo,
                               const float* __restrict__ bias,
                               float* __restrict__ out, int G) {
    int tm = threadIdx.x >> 6;                  // 4 rows / block
    int tn = threadIdx.x & 63;                  // 64 cols / block
    int m = blockIdx.x * 4 + tm;
    int n = blockIdx.y * 64 + tn;
    if (m >= G) return;
    const float* a = A + (size_t)m * 512;
    const u16* wh = WThi + (size_t)n * 512;
    const u16* wl = WTlo + (size_t)n * 512;
    float acc = 0.f;
    for (int k = 0; k < 512; k += 4) {
        float4 av = *reinterpret_cast<const float4*>(a + k);
        ushort4 h4 = *reinterpret_cast<const ushort4*>(wh + k);
        ushort4 l4 = *reinterpret_cast<const ushort4*>(wl + k);
        acc += av.x * (bf2f(h4.x) + bf2f(l4.x));
        acc += av.y * (bf2f(h4.y) + bf2f(l4.y));
        acc += av.z * (bf2f(h4.z) + bf2f(l4.z));
        acc += av.w * (bf2f(h4.w) + bf2f(l4.w));
    }
    out[(size_t)m * 512 + n] = tanhf(acc + bias[n]);
}

// =========================== Launcher ==============================
extern "C" void kernel_launch(void* const* d_in, const int* in_sizes, int n_in,
                              void* d_out, int out_size, void* d_ws, size_t ws_size,
                              hipStream_t stream) {
    const float* x      = (const float*)d_in[0];
    const void*  ei     = d_in[1];
    const void*  batch  = d_in[2];
    const float* W1a    = (const float*)d_in[3];
    const float* b1a    = (const float*)d_in[4];
    const float* W1b    = (const float*)d_in[5];
    const float* b1b    = (const float*)d_in[6];
    const float* Wa     = (const float*)d_in[7];
    const float* ba     = (const float*)d_in[8];
    const float* Wb     = (const float*)d_in[9];
    const float* bb     = (const float*)d_in[10];
    const float* gammas = (const float*)d_in[11];
    const float* betas  = (const float*)d_in[12];
    const float* fcW    = (const float*)d_in[13];
    const float* fcb    = (const float*)d_in[14];

    const int N = in_sizes[2];                 // 50000 nodes
    const int E = in_sizes[1] / 2;             // 150000 edges
    const int F = in_sizes[0] / N;             // 128
    const int G = out_size / 512;              // 256 graphs

    // ---- workspace (bump allocator, 256B aligned) ----
    char* w = (char*)d_ws;
    size_t off = 0;
    auto alloc = [&](size_t bytes) -> void* {
        void* p = w + off;
        off = (off + bytes + 255) & ~(size_t)255;
        return p;
    };
    // two big slots; each holds either H (f32 N x 512) or a split-bf16 pair
    float* slotA  = (float*)alloc((size_t)N * 512 * 4);
    float* slotB  = (float*)alloc((size_t)N * 512 * 4);
    int*   row_ofs= (int*)alloc((size_t)(N + 1) * 4);
    int*   cnt    = (int*)alloc((size_t)N * 4);       // reused as cursor
    int*   esrc   = (int*)alloc((size_t)E * 4);
    int*   cg     = (int*)alloc((size_t)G * 4);
    float* stats  = (float*)alloc(1024 * 4);
    float* scale  = (float*)alloc(512 * 4);
    float* shift  = (float*)alloc(512 * 4);
    float* pooled = (float*)alloc((size_t)G * 512 * 4);
    float* Apool  = (float*)alloc((size_t)G * 512 * 4);
    int*   flag   = (int*)alloc(256);
    // transposed split weights: 5 gemm1 + 5 gemm2 + fc (each 512x512 worst case)
    const size_t WSZ = (size_t)512 * 512;
    u16* g1h[5]; u16* g1l[5]; u16* g2h[5]; u16* g2l[5];
    for (int i = 0; i < 5; ++i) {
        g1h[i] = (u16*)alloc(WSZ * 2); g1l[i] = (u16*)alloc(WSZ * 2);
        g2h[i] = (u16*)alloc(WSZ * 2); g2l[i] = (u16*)alloc(WSZ * 2);
    }
    u16* fch = (u16*)alloc(WSZ * 2); u16* fcl = (u16*)alloc(WSZ * 2);
    (void)ws_size; (void)n_in;

    // ---- weight transpose + split (cheap, every call) ----
    {
        dim3 gK128(128 / 32, 512 / 32), gK512(512 / 32, 512 / 32);
        transpose_split_kernel<<<gK128, 256, 0, stream>>>(W1a, 128, 512, g1h[0], g1l[0]);
        transpose_split_kernel<<<gK512, 256, 0, stream>>>(W1b, 512, 512, g2h[0], g2l[0]);
        for (int i = 0; i < 4; ++i) {
            transpose_split_kernel<<<gK512, 256, 0, stream>>>(Wa + (size_t)i * WSZ, 512, 512,
                                                              g1h[i + 1], g1l[i + 1]);
            transpose_split_kernel<<<gK512, 256, 0, stream>>>(Wb + (size_t)i * WSZ, 512, 512,
                                                              g2h[i + 1], g2l[i + 1]);
        }
        transpose_split_kernel<<<gK512, 256, 0, stream>>>(fcW, 512, 512, fch, fcl);
    }

    // ---- int width detection + CSR build ----
    detect_kernel<<<1, 256, 0, stream>>>((const int*)ei, E, flag);
    hipMemsetAsync(cnt, 0, (size_t)N * 4, stream);
    hist_kernel<<<(E + 255) / 256, 256, 0, stream>>>(ei, (long long)E, flag, cnt, E);
    scan_kernel<<<1, 1024, 0, stream>>>(cnt, row_ofs, N);
    copy_int_kernel<<<(N + 255) / 256, 256, 0, stream>>>(row_ofs, cnt, N);
    fill_csr_kernel<<<(E + 255) / 256, 256, 0, stream>>>(ei, (long long)E, flag, cnt, esrc, E);
    hipMemsetAsync(cg, 0, (size_t)G * 4, stream);
    hist_kernel<<<(N + 255) / 256, 256, 0, stream>>>(batch, 0, flag, cg, N);

    // ---- 5 GIN blocks ----
    // slots rotate: agg(curH -> Z in zslot), gemm1(Z -> T in tslot), gemm2(T -> H in zslot)
    const float* curH = x;
    float* zslot = slotA;
    float* tslot = slotB;
    int ncols = F;
    const float* scaleP = nullptr;
    const float* shiftP = nullptr;
    const int mblk = (N + 127) / 128;
    dim3 ggrid(4, mblk);

    for (int L = 0; L < 5; ++L) {
        u16* Zhi = (u16*)zslot; u16* Zlo = Zhi + (size_t)N * 512;
        u16* Thi = (u16*)tslot; u16* Tlo = Thi + (size_t)N * 512;
        float* H = zslot;

        int tpr = ncols / 4;
        int nper = 128 / tpr;
        aggregate_split_kernel<<<(N + nper - 1) / nper, 128, 0, stream>>>(
            curH, row_ofs, esrc, scaleP, shiftP, Zhi, Zlo, N, ncols);

        const float* ba_ = (L == 0) ? b1a : ba + (size_t)(L - 1) * 512;
        const float* bb_ = (L == 0) ? b1b : bb + (size_t)(L - 1) * 512;

        gemm_mfma<0><<<ggrid, 256, 0, stream>>>(Zhi, Zlo, g1h[L], g1l[L], ba_,
                                                N, ncols, Thi, Tlo, nullptr, nullptr);
        hipMemsetAsync(stats, 0, 1024 * 4, stream);
        gemm_mfma<1><<<ggrid, 256, 0, stream>>>(Thi, Tlo, g2h[L], g2l[L], bb_,
                                                N, 512, nullptr, nullptr, H, stats);
        bn_params_kernel<<<2, 256, 0, stream>>>(stats, gammas + (size_t)L * 512,
                                                betas + (size_t)L * 512,
                                                scale, shift, 1.f / (float)N);
        curH = H;
        ncols = 512;
        scaleP = scale;
        shiftP = shift;
        float* tmp = zslot; zslot = tslot; tslot = tmp;
    }
    const float* Hfin = curH;

    // ---- global mean pool (+ fold BN5 affine) ----
    hipMemsetAsync(pooled, 0, (size_t)G * 512 * 4, stream);
    pool_kernel<<<(N + POOL_ROWS - 1) / POOL_ROWS, 128, 0, stream>>>(Hfin, batch, flag, pooled, N);
    int total = G * 512;
    finalize_pool_kernel<<<(total + 255) / 256, 256, 0, stream>>>(pooled, cg, scale, shift,
                                                                  Apool, total);

    // ---- final fc + tanh ----
    dim3 fgrid((G + 3) / 4, 512 / 64);
    fc_tanh_kernel<<<fgrid, 256, 0, stream>>>(Apool, fch, fcl, fcb, (float*)d_out, G);
}

// Round 7
// 1572.283 us; speedup vs baseline: 2.6300x; 1.1863x over previous
//
#include <hip/hip_runtime.h>
#include <math.h>

typedef unsigned short u16;
typedef unsigned int u32;
typedef __attribute__((ext_vector_type(8))) short bf16x8;   // 8 bf16 = 4 VGPRs
typedef __attribute__((ext_vector_type(4))) float f32x4;

__device__ __forceinline__ u16 f2bf(float x) {              // RNE float->bf16
    u32 u = __float_as_uint(x);
    return (u16)((u + 0x7FFFu + ((u >> 16) & 1u)) >> 16);
}
__device__ __forceinline__ float bf2f(u16 h) {
    return __uint_as_float(((u32)h) << 16);
}
__device__ __forceinline__ void async16(const void* g, void* l) {
    __builtin_amdgcn_global_load_lds((const __attribute__((address_space(1))) void*)g,
                                     (__attribute__((address_space(3))) void*)l,
                                     16, 0, 0);
}

// ==================== int32/int64 index handling ====================
__device__ __forceinline__ int idx_at(const void* p, long long i, int is64) {
    if (is64) return (int)((const long long*)p)[i];
    return ((const int*)p)[i];
}

__global__ void detect_kernel(const int* __restrict__ ei, int E, int* __restrict__ flag) {
    __shared__ int any;
    if (threadIdx.x == 0) any = 0;
    __syncthreads();
    int n = min(E, 1024);
    for (int i = threadIdx.x; i < n; i += blockDim.x)
        if (ei[2 * i + 1] != 0) any = 1;
    __syncthreads();
    if (threadIdx.x == 0) *flag = (any == 0) ? 1 : 0;
}

// ============================ CSR build ============================
__global__ void hist_kernel(const void* __restrict__ idx, long long offs,
                            const int* __restrict__ flag,
                            int* __restrict__ cnt, int n) {
    int is64 = *flag;
    int i = blockIdx.x * blockDim.x + threadIdx.x;
    if (i < n) atomicAdd(&cnt[idx_at(idx, offs + i, is64)], 1);
}

// -------- two-level scan: ofs[i+1] = inclusive_sum(cnt[0..i]), ofs[0]=0 -----
// scan1: 256 thr x 4 elems = 1024/block; block-local inclusive into ofs[i+1]
__global__ void scan1_kernel(const int* __restrict__ cnt, int* __restrict__ ofs,
                             int* __restrict__ bsum, int n) {
    __shared__ int s[256];
    int b = blockIdx.x, t = threadIdx.x;
    int base = b * 1024 + t * 4;
    int v0 = (base + 0 < n) ? cnt[base + 0] : 0;
    int v1 = (base + 1 < n) ? cnt[base + 1] : 0;
    int v2 = (base + 2 < n) ? cnt[base + 2] : 0;
    int v3 = (base + 3 < n) ? cnt[base + 3] : 0;
    int tsum = v0 + v1 + v2 + v3;
    s[t] = tsum;
    __syncthreads();
    for (int off = 1; off < 256; off <<= 1) {
        int u = (t >= off) ? s[t - off] : 0;
        __syncthreads();
        s[t] += u;
        __syncthreads();
    }
    int pre = s[t] - tsum;
    int e0 = pre + v0, e1 = e0 + v1, e2 = e1 + v2, e3 = e2 + v3;
    if (base + 0 < n) ofs[base + 1] = e0;
    if (base + 1 < n) ofs[base + 2] = e1;
    if (base + 2 < n) ofs[base + 3] = e2;
    if (base + 3 < n) ofs[base + 4] = e3;
    if (t == 255) bsum[b] = s[255];
    if (b == 0 && t == 0) ofs[0] = 0;
}

// scan2: single wave exclusive-scans block sums (supports nb <= 64, i.e. n <= 65536)
__global__ void scan2_kernel(int* __restrict__ bsum, int nb) {
    int t = threadIdx.x;                       // 64 threads
    int orig = (t < nb) ? bsum[t] : 0;
    int v = orig;
    for (int d = 1; d < 64; d <<= 1) {
        int u = __shfl_up(v, d);
        if (t >= d) v += u;
    }
    if (t < nb) bsum[t] = v - orig;            // exclusive offset
}

// scan3: add block offsets
__global__ void scan3_kernel(int* __restrict__ ofs, const int* __restrict__ bsum, int n) {
    int i = blockIdx.x * blockDim.x + threadIdx.x;
    if (i < n) ofs[i + 1] += bsum[i >> 10];
}

__global__ void fill_csr_kernel(const void* __restrict__ ei, long long E,
                                const int* __restrict__ flag,
                                int* __restrict__ cursor, int* __restrict__ esrc, int e) {
    int is64 = *flag;
    int i = blockIdx.x * blockDim.x + threadIdx.x;
    if (i < e) {
        int d = idx_at(ei, E + i, is64);
        int s = idx_at(ei, i, is64);
        int p = atomicAdd(&cursor[d], 1);
        esrc[p] = s;
    }
}

__global__ void copy_int_kernel(const int* __restrict__ a, int* __restrict__ b, int n) {
    int i = blockIdx.x * blockDim.x + threadIdx.x;
    if (i < n) b[i] = a[i];
}

// ================ Aggregation (GIN) + BN fold + bf16 split ================
// z = scale*(u_i + sum_j u_j) + (1+deg)*shift   (scale==nullptr -> identity)
__global__ void aggregate_split_kernel(const float* __restrict__ X,
                                       const int* __restrict__ row_ofs,
                                       const int* __restrict__ esrc,
                                       const float* __restrict__ scale,
                                       const float* __restrict__ shift,
                                       u16* __restrict__ Zhi, u16* __restrict__ Zlo,
                                       int n, int ncols) {
    int tpr = ncols >> 2;                       // threads per row (float4 each)
    int nper = 256 / tpr;                       // rows per block
    int node = blockIdx.x * nper + threadIdx.x / tpr;
    int c = (threadIdx.x % tpr) * 4;
    if (node >= n) return;
    int beg = row_ofs[node], end = row_ofs[node + 1];
    float4 acc = *reinterpret_cast<const float4*>(X + (size_t)node * ncols + c);
    int e = beg;
    for (; e + 1 < end; e += 2) {               // 2x unroll: independent gathers
        int s0 = esrc[e], s1 = esrc[e + 1];
        float4 a = *reinterpret_cast<const float4*>(X + (size_t)s0 * ncols + c);
        float4 b = *reinterpret_cast<const float4*>(X + (size_t)s1 * ncols + c);
        acc.x += a.x + b.x; acc.y += a.y + b.y;
        acc.z += a.z + b.z; acc.w += a.w + b.w;
    }
    if (e < end) {
        int s0 = esrc[e];
        float4 a = *reinterpret_cast<const float4*>(X + (size_t)s0 * ncols + c);
        acc.x += a.x; acc.y += a.y; acc.z += a.z; acc.w += a.w;
    }
    if (scale) {
        float d1 = (float)(end - beg + 1);
        float4 sc = *reinterpret_cast<const float4*>(scale + c);
        float4 sh = *reinterpret_cast<const float4*>(shift + c);
        acc.x = sc.x * acc.x + d1 * sh.x;
        acc.y = sc.y * acc.y + d1 * sh.y;
        acc.z = sc.z * acc.z + d1 * sh.z;
        acc.w = sc.w * acc.w + d1 * sh.w;
    }
    ushort4 hv, lv;
    hv.x = f2bf(acc.x); lv.x = f2bf(acc.x - bf2f(hv.x));
    hv.y = f2bf(acc.y); lv.y = f2bf(acc.y - bf2f(hv.y));
    hv.z = f2bf(acc.z); lv.z = f2bf(acc.z - bf2f(hv.z));
    hv.w = f2bf(acc.w); lv.w = f2bf(acc.w - bf2f(hv.w));
    *reinterpret_cast<ushort4*>(Zhi + (size_t)node * ncols + c) = hv;
    *reinterpret_cast<ushort4*>(Zlo + (size_t)node * ncols + c) = lv;
}

// ============== Weight transpose + bf16 split ==============
// W (K x N, f32) -> WT_hi/WT_lo (N x K, bf16)
__global__ void transpose_split_kernel(const float* __restrict__ W, int K, int N,
                                       u16* __restrict__ Thi, u16* __restrict__ Tlo) {
    __shared__ float t[32][33];
    int k0 = blockIdx.x * 32, n0 = blockIdx.y * 32;
    int tx = threadIdx.x & 31, ty = threadIdx.x >> 5;      // 32 x 8
#pragma unroll
    for (int i = 0; i < 32; i += 8)
        t[ty + i][tx] = W[(size_t)(k0 + ty + i) * N + n0 + tx];
    __syncthreads();
#pragma unroll
    for (int i = 0; i < 32; i += 8) {
        float v = t[tx][ty + i];
        size_t o = (size_t)(n0 + ty + i) * K + k0 + tx;
        u16 h = f2bf(v);
        Thi[o] = h;
        Tlo[o] = f2bf(v - bf2f(h));
    }
}

// batched version for the ten 512x512 weights (one launch)
struct TBatch {
    const float* src[10];
    u16* dh[10];
    u16* dl[10];
};
__global__ void transpose_split_batch_kernel(TBatch tb) {
    __shared__ float t[32][33];
    int z = blockIdx.z;
    const float* W = tb.src[z];
    u16* Thi = tb.dh[z];
    u16* Tlo = tb.dl[z];
    int k0 = blockIdx.x * 32, n0 = blockIdx.y * 32;
    int tx = threadIdx.x & 31, ty = threadIdx.x >> 5;
#pragma unroll
    for (int i = 0; i < 32; i += 8)
        t[ty + i][tx] = W[(size_t)(k0 + ty + i) * 512 + n0 + tx];
    __syncthreads();
#pragma unroll
    for (int i = 0; i < 32; i += 8) {
        float v = t[tx][ty + i];
        size_t o = (size_t)(n0 + ty + i) * 512 + k0 + tx;
        u16 h = f2bf(v);
        Thi[o] = h;
        Tlo[o] = f2bf(v - bf2f(h));
    }
}

// ======================= split-bf16 MFMA GEMM =======================
// C[M x 512] = act(A @ W + bias); A = (Ahi+Alo) M x K bf16 row-major;
// WT = (Bhi+Blo) 512 x K bf16 row-major. 3-term Markidis, fp32 accumulate.
// MODE 0: relu -> split-bf16 out.  MODE 1: relu -> f32 out + fused BN col stats.
// 1-D grid, remapped so the 4 N-blocks of one M-tile share an XCD (bid%8 const):
//   grp=bid>>5; pos=bid&31; mtile=grp*8+(pos&7); nblk=pos>>3
// BK=32 -> 32 KB LDS -> ~4-5 blocks/CU (occupancy-driven overlap).
template <int MODE>
__global__ __launch_bounds__(256, 4)
void gemm_mfma(const u16* __restrict__ Ahi, const u16* __restrict__ Alo,
               const u16* __restrict__ Bhi, const u16* __restrict__ Blo,
               const float* __restrict__ bias, int M, int K, int mblk,
               u16* __restrict__ Ohi, u16* __restrict__ Olo,
               float* __restrict__ Of32, float* __restrict__ stats) {
    __shared__ __align__(16) char lds[32768];
    char* ldsAhi = lds;
    char* ldsAlo = lds + 8192;
    char* ldsBhi = lds + 16384;
    char* ldsBlo = lds + 24576;

    const int bid = blockIdx.x;
    const int mt = (bid >> 5) * 8 + (bid & 7);
    const int nb = (bid & 31) >> 3;
    if (mt >= mblk) return;
    const int row0 = mt * 128;
    const int col0 = nb * 128;

    const int tid = threadIdx.x;
    const int lane = tid & 63;
    const int wave = tid >> 6;
    const int wr = wave >> 1, wc = wave & 1;   // 2x2 waves, each 64x64 out

    f32x4 acc[4][4];
#pragma unroll
    for (int mi = 0; mi < 4; ++mi)
#pragma unroll
        for (int ni = 0; ni < 4; ++ni)
            acc[mi][ni] = (f32x4){0.f, 0.f, 0.f, 0.f};

    const int nkt = K >> 5;                    // BK = 32
    for (int kt = 0; kt < nkt; ++kt) {
        const int k0 = kt << 5;
        // ---- stage 4 tiles (128x32 bf16 = 8KB each) via global_load_lds ----
        // row has 4 16B-chunks; source pre-swizzled: slot s holds chunk s^(row&3)
#pragma unroll
        for (int i = 0; i < 2; ++i) {
            int c = tid + i * 256;             // 0..511
            int row = c >> 2, s = c & 3;
            int ks = ((s ^ (row & 3)) << 3);   // element offset in BK
            int ar = row0 + row; if (ar > M - 1) ar = M - 1;
            size_t aoff = (size_t)ar * K + k0 + ks;
            size_t boff = (size_t)(col0 + row) * K + k0 + ks;
            async16(Ahi + aoff, ldsAhi + c * 16);
            async16(Alo + aoff, ldsAlo + c * 16);
            async16(Bhi + boff, ldsBhi + c * 16);
            async16(Blo + boff, ldsBlo + c * 16);
        }
        __syncthreads();                        // drains vmcnt before barrier
        // ---- one K=32 MFMA pass ----
        {
            bf16x8 ah[4], al[4], bh[4], bl[4];
            const int kc = lane >> 4;          // 8-elem chunk idx (0..3)
#pragma unroll
            for (int mi = 0; mi < 4; ++mi) {
                int ml = wr * 64 + mi * 16 + (lane & 15);
                int off = ml * 64 + ((kc ^ (ml & 3)) << 4);
                ah[mi] = *(const bf16x8*)(ldsAhi + off);
                al[mi] = *(const bf16x8*)(ldsAlo + off);
            }
#pragma unroll
            for (int ni = 0; ni < 4; ++ni) {
                int nl = wc * 64 + ni * 16 + (lane & 15);
                int off = nl * 64 + ((kc ^ (nl & 3)) << 4);
                bh[ni] = *(const bf16x8*)(ldsBhi + off);
                bl[ni] = *(const bf16x8*)(ldsBlo + off);
            }
#pragma unroll
            for (int mi = 0; mi < 4; ++mi)
#pragma unroll
                for (int ni = 0; ni < 4; ++ni) {
                    acc[mi][ni] = __builtin_amdgcn_mfma_f32_16x16x32_bf16(
                        ah[mi], bh[ni], acc[mi][ni], 0, 0, 0);
                    acc[mi][ni] = __builtin_amdgcn_mfma_f32_16x16x32_bf16(
                        ah[mi], bl[ni], acc[mi][ni], 0, 0, 0);
                    acc[mi][ni] = __builtin_amdgcn_mfma_f32_16x16x32_bf16(
                        al[mi], bh[ni], acc[mi][ni], 0, 0, 0);
                }
        }
        __syncthreads();
    }

    // ---- epilogue: C/D layout col=lane&15, row=(lane>>4)*4+reg [m89] ----
    const int cl = lane & 15;
    const int rb = (lane >> 4) * 4;
    if (MODE == 0) {
#pragma unroll
        for (int ni = 0; ni < 4; ++ni) {
            int gc = col0 + wc * 64 + ni * 16 + cl;
            float bv = bias[gc];
#pragma unroll
            for (int mi = 0; mi < 4; ++mi) {
                int gr0 = row0 + wr * 64 + mi * 16 + rb;
#pragma unroll
                for (int r = 0; r < 4; ++r) {
                    int gr = gr0 + r;
                    if (gr < M) {
                        float v = fmaxf(acc[mi][ni][r] + bv, 0.f);
                        u16 h = f2bf(v);
                        Ohi[(size_t)gr * 512 + gc] = h;
                        Olo[(size_t)gr * 512 + gc] = f2bf(v - bf2f(h));
                    }
                }
            }
        }
    } else {
#pragma unroll
        for (int ni = 0; ni < 4; ++ni) {
            int gc = col0 + wc * 64 + ni * 16 + cl;
            float bv = bias[gc];
            float s = 0.f, q = 0.f;
#pragma unroll
            for (int mi = 0; mi < 4; ++mi) {
                int gr0 = row0 + wr * 64 + mi * 16 + rb;
#pragma unroll
                for (int r = 0; r < 4; ++r) {
                    int gr = gr0 + r;
                    if (gr < M) {
                        float v = fmaxf(acc[mi][ni][r] + bv, 0.f);
                        Of32[(size_t)gr * 512 + gc] = v;
                        s += v; q += v * v;
                    }
                }
            }
            s += __shfl_xor(s, 16); s += __shfl_xor(s, 32);
            q += __shfl_xor(q, 16); q += __shfl_xor(q, 32);
            if (lane < 16) {
                atomicAdd(&stats[gc], s);
                atomicAdd(&stats[512 + gc], q);
            }
        }
    }
}

// ======================= BN params from stats =======================
__global__ void bn_params_kernel(const float* __restrict__ stats,
                                 const float* __restrict__ gamma,
                                 const float* __restrict__ beta,
                                 float* __restrict__ scale, float* __restrict__ shift,
                                 float invN) {
    int c = blockIdx.x * blockDim.x + threadIdx.x;
    if (c >= 512) return;
    float mean = stats[c] * invN;
    float var = fmaxf(stats[512 + c] * invN - mean * mean, 0.f);
    float a = gamma[c] * rsqrtf(var + 1e-5f);
    scale[c] = a;
    shift[c] = beta[c] - mean * a;
}

// =========================== Pooling ===============================
#define POOL_ROWS 64
__global__ void pool_kernel(const float* __restrict__ H, const void* __restrict__ batch,
                            const int* __restrict__ flag,
                            float* __restrict__ pooled, int n) {
    int is64 = *flag;
    int c = threadIdx.x * 4;
    int r0 = blockIdx.x * POOL_ROWS;
    if (r0 >= n) return;
    int r1 = min(r0 + POOL_ROWS, n);
    int g = idx_at(batch, r0, is64);
    float4 acc = make_float4(0.f, 0.f, 0.f, 0.f);
    for (int r = r0; r < r1; ++r) {
        int gr = idx_at(batch, r, is64);
        if (gr != g) {
            atomicAdd(&pooled[(size_t)g * 512 + c + 0], acc.x);
            atomicAdd(&pooled[(size_t)g * 512 + c + 1], acc.y);
            atomicAdd(&pooled[(size_t)g * 512 + c + 2], acc.z);
            atomicAdd(&pooled[(size_t)g * 512 + c + 3], acc.w);
            acc = make_float4(0.f, 0.f, 0.f, 0.f);
            g = gr;
        }
        float4 v = *reinterpret_cast<const float4*>(H + (size_t)r * 512 + c);
        acc.x += v.x; acc.y += v.y; acc.z += v.z; acc.w += v.w;
    }
    atomicAdd(&pooled[(size_t)g * 512 + c + 0], acc.x);
    atomicAdd(&pooled[(size_t)g * 512 + c + 1], acc.y);
    atomicAdd(&pooled[(size_t)g * 512 + c + 2], acc.z);
    atomicAdd(&pooled[(size_t)g * 512 + c + 3], acc.w);
}

__global__ void finalize_pool_kernel(const float* __restrict__ pooled,
                                     const int* __restrict__ cg,
                                     const float* __restrict__ scale,
                                     const float* __restrict__ shift,
                                     float* __restrict__ Apool, int total) {
    int idx = blockIdx.x * blockDim.x + threadIdx.x;
    if (idx >= total) return;
    int g = idx >> 9;
    int c = idx & 511;
    float cnt = fmaxf((float)cg[g], 1.f);
    Apool[idx] = scale[c] * (pooled[idx] / cnt) + shift[c];
}

// ================== final fc + tanh (small M, fp32 acc) ==================
__global__ void fc_tanh_kernel(const float* __restrict__ A,
                               const u16* __restrict__ WThi, const u16* __restrict__ WTlo,
                               const float* __restrict__ bias,
                               float* __restrict__ out, int G) {
    int tm = threadIdx.x >> 6;                  // 4 rows / block
    int tn = threadIdx.x & 63;                  // 64 cols / block
    int m = blockIdx.x * 4 + tm;
    int n = blockIdx.y * 64 + tn;
    if (m >= G) return;
    const float* a = A + (size_t)m * 512;
    const u16* wh = WThi + (size_t)n * 512;
    const u16* wl = WTlo + (size_t)n * 512;
    float acc = 0.f;
    for (int k = 0; k < 512; k += 4) {
        float4 av = *reinterpret_cast<const float4*>(a + k);
        ushort4 h4 = *reinterpret_cast<const ushort4*>(wh + k);
        ushort4 l4 = *reinterpret_cast<const ushort4*>(wl + k);
        acc += av.x * (bf2f(h4.x) + bf2f(l4.x));
        acc += av.y * (bf2f(h4.y) + bf2f(l4.y));
        acc += av.z * (bf2f(h4.z) + bf2f(l4.z));
        acc += av.w * (bf2f(h4.w) + bf2f(l4.w));
    }
    out[(size_t)m * 512 + n] = tanhf(acc + bias[n]);
}

// =========================== Launcher ==============================
extern "C" void kernel_launch(void* const* d_in, const int* in_sizes, int n_in,
                              void* d_out, int out_size, void* d_ws, size_t ws_size,
                              hipStream_t stream) {
    const float* x      = (const float*)d_in[0];
    const void*  ei     = d_in[1];
    const void*  batch  = d_in[2];
    const float* W1a    = (const float*)d_in[3];
    const float* b1a    = (const float*)d_in[4];
    const float* W1b    = (const float*)d_in[5];
    const float* b1b    = (const float*)d_in[6];
    const float* Wa     = (const float*)d_in[7];
    const float* ba     = (const float*)d_in[8];
    const float* Wb     = (const float*)d_in[9];
    const float* bb     = (const float*)d_in[10];
    const float* gammas = (const float*)d_in[11];
    const float* betas  = (const float*)d_in[12];
    const float* fcW    = (const float*)d_in[13];
    const float* fcb    = (const float*)d_in[14];

    const int N = in_sizes[2];                 // 50000 nodes
    const int E = in_sizes[1] / 2;             // 150000 edges
    const int F = in_sizes[0] / N;             // 128
    const int G = out_size / 512;              // 256 graphs

    // ---- workspace (bump allocator, 256B aligned) ----
    char* w = (char*)d_ws;
    size_t off = 0;
    auto alloc = [&](size_t bytes) -> void* {
        void* p = w + off;
        off = (off + bytes + 255) & ~(size_t)255;
        return p;
    };
    float* slotA  = (float*)alloc((size_t)N * 512 * 4);
    float* slotB  = (float*)alloc((size_t)N * 512 * 4);
    int*   row_ofs= (int*)alloc((size_t)(N + 1) * 4);
    int*   cnt    = (int*)alloc((size_t)N * 4);       // reused as cursor
    int*   esrc   = (int*)alloc((size_t)E * 4);
    int*   cg     = (int*)alloc((size_t)G * 4);
    int*   bsum   = (int*)alloc(256 * 4);
    float* stats  = (float*)alloc(1024 * 4);
    float* scale  = (float*)alloc(512 * 4);
    float* shift  = (float*)alloc(512 * 4);
    float* pooled = (float*)alloc((size_t)G * 512 * 4);
    float* Apool  = (float*)alloc((size_t)G * 512 * 4);
    int*   flag   = (int*)alloc(256);
    const size_t WSZ = (size_t)512 * 512;
    u16* g1h[5]; u16* g1l[5]; u16* g2h[5]; u16* g2l[5];
    for (int i = 0; i < 5; ++i) {
        g1h[i] = (u16*)alloc(WSZ * 2); g1l[i] = (u16*)alloc(WSZ * 2);
        g2h[i] = (u16*)alloc(WSZ * 2); g2l[i] = (u16*)alloc(WSZ * 2);
    }
    u16* fch = (u16*)alloc(WSZ * 2); u16* fcl = (u16*)alloc(WSZ * 2);
    (void)ws_size; (void)n_in;

    // ---- weight transpose + split (W1a separate; ten 512x512 batched) ----
    {
        dim3 gK128(128 / 32, 512 / 32);
        transpose_split_kernel<<<gK128, 256, 0, stream>>>(W1a, 128, 512, g1h[0], g1l[0]);
        TBatch tb;
        tb.src[0] = W1b; tb.dh[0] = g2h[0]; tb.dl[0] = g2l[0];
        for (int i = 0; i < 4; ++i) {
            tb.src[1 + i] = Wa + (size_t)i * WSZ; tb.dh[1 + i] = g1h[i + 1]; tb.dl[1 + i] = g1l[i + 1];
            tb.src[5 + i] = Wb + (size_t)i * WSZ; tb.dh[5 + i] = g2h[i + 1]; tb.dl[5 + i] = g2l[i + 1];
        }
        tb.src[9] = fcW; tb.dh[9] = fch; tb.dl[9] = fcl;
        dim3 gB(16, 16, 10);
        transpose_split_batch_kernel<<<gB, 256, 0, stream>>>(tb);
    }

    // ---- int width detection + CSR build ----
    detect_kernel<<<1, 256, 0, stream>>>((const int*)ei, E, flag);
    hipMemsetAsync(cnt, 0, (size_t)N * 4, stream);
    hist_kernel<<<(E + 255) / 256, 256, 0, stream>>>(ei, (long long)E, flag, cnt, E);
    int nb = (N + 1023) / 1024;                // <= 64 (N <= 65536)
    scan1_kernel<<<nb, 256, 0, stream>>>(cnt, row_ofs, bsum, N);
    scan2_kernel<<<1, 64, 0, stream>>>(bsum, nb);
    scan3_kernel<<<(N + 255) / 256, 256, 0, stream>>>(row_ofs, bsum, N);
    copy_int_kernel<<<(N + 255) / 256, 256, 0, stream>>>(row_ofs, cnt, N);
    fill_csr_kernel<<<(E + 255) / 256, 256, 0, stream>>>(ei, (long long)E, flag, cnt, esrc, E);
    hipMemsetAsync(cg, 0, (size_t)G * 4, stream);
    hist_kernel<<<(N + 255) / 256, 256, 0, stream>>>(batch, 0, flag, cg, N);

    // ---- 5 GIN blocks ----
    const float* curH = x;
    float* zslot = slotA;
    float* tslot = slotB;
    int ncols = F;
    const float* scaleP = nullptr;
    const float* shiftP = nullptr;
    const int mblk = (N + 127) / 128;
    const int ngrp = (mblk + 7) / 8;
    dim3 ggrid(ngrp * 32);

    for (int L = 0; L < 5; ++L) {
        u16* Zhi = (u16*)zslot; u16* Zlo = Zhi + (size_t)N * 512;
        u16* Thi = (u16*)tslot; u16* Tlo = Thi + (size_t)N * 512;
        float* H = zslot;

        int tpr = ncols / 4;
        int nper = 256 / tpr;
        aggregate_split_kernel<<<(N + nper - 1) / nper, 256, 0, stream>>>(
            curH, row_ofs, esrc, scaleP, shiftP, Zhi, Zlo, N, ncols);

        const float* ba_ = (L == 0) ? b1a : ba + (size_t)(L - 1) * 512;
        const float* bb_ = (L == 0) ? b1b : bb + (size_t)(L - 1) * 512;

        gemm_mfma<0><<<ggrid, 256, 0, stream>>>(Zhi, Zlo, g1h[L], g1l[L], ba_,
                                                N, ncols, mblk, Thi, Tlo, nullptr, nullptr);
        hipMemsetAsync(stats, 0, 1024 * 4, stream);
        gemm_mfma<1><<<ggrid, 256, 0, stream>>>(Thi, Tlo, g2h[L], g2l[L], bb_,
                                                N, 512, mblk, nullptr, nullptr, H, stats);
        bn_params_kernel<<<2, 256, 0, stream>>>(stats, gammas + (size_t)L * 512,
                                                betas + (size_t)L * 512,
                                                scale, shift, 1.f / (float)N);
        curH = H;
        ncols = 512;
        scaleP = scale;
        shiftP = shift;
        float* tmp = zslot; zslot = tslot; tslot = tmp;
    }
    const float* Hfin = curH;

    // ---- global mean pool (+ fold BN5 affine) ----
    hipMemsetAsync(pooled, 0, (size_t)G * 512 * 4, stream);
    pool_kernel<<<(N + POOL_ROWS - 1) / POOL_ROWS, 128, 0, stream>>>(Hfin, batch, flag, pooled, N);
    int total = G * 512;
    finalize_pool_kernel<<<(total + 255) / 256, 256, 0, stream>>>(pooled, cg, scale, shift,
                                                                  Apool, total);

    // ---- final fc + tanh ----
    dim3 fgrid((G + 3) / 4, 512 / 64);
    fc_tanh_kernel<<<fgrid, 256, 0, stream>>>(Apool, fch, fcl, fcb, (float*)d_out, G);
}